// Round 2
// baseline (412.398 us; speedup 1.0000x reference)
//
#include <hip/hip_runtime.h>

#define NN 32      // nodes
#define FF 64      // GAT out features
#define HH 128     // LSTM hidden
#define G4 512     // 4*H
#define BB 32      // batch
#define TT 512     // time steps
#define ET 128     // 96 edges + 32 self loops
#define NPOS (BB*TT)

__device__ __forceinline__ float frcp(float x) { return __builtin_amdgcn_rcpf(x); }

// ---------------- prep: fold GAT linear into LSTM input weights + Wt transpose ----------------
// R15 weight layout (DPP ring-share): lstm thread tid = r*4+kq (512 threads), lr = r&3.
// Lane holds h sub-block b = (lr - s) & 3 at macro-step s (row_ror:4 brings lane i-4's regs).
// Wt[tid*128 + s*32 + j*8 + g*2 + e] = W_hh[(kq*32 + 8*((lr-s)&3) + 2*j + e)][g*128 + r]
__global__ __launch_bounds__(512) void prep_kernel(const float* __restrict__ w_gat,
                                                   const float* __restrict__ b_gat,
                                                   const float* __restrict__ W_ih,
                                                   const float* __restrict__ W_hh,
                                                   float* __restrict__ W_eff,
                                                   float* __restrict__ biasp,
                                                   float* __restrict__ Wt) {
  int j = threadIdx.x;
  int n = blockIdx.x;
  float accw = 0.f, accb = 0.f;
#pragma unroll 8
  for (int f = 0; f < FF; ++f) {
    float wv = W_ih[(n * FF + f) * G4 + j];
    accw = fmaf(w_gat[f], wv, accw);
    accb = fmaf(b_gat[f], wv, accb);
  }
  W_eff[n * G4 + j] = accw;
  biasp[n * G4 + j] = accb;
  int g0 = (n * G4 + j) * 4;
#pragma unroll
  for (int q = 0; q < 4; ++q) {
    int E = g0 + q;
    int tl = E >> 7;          // lstm thread 0..511
    int idx = E & 127;
    int s = idx >> 5;         // macro-step 0..3
    int jj = (idx >> 3) & 3;  // pair within sub-block
    int g = (idx >> 1) & 3;   // gate
    int e = idx & 1;
    int r = tl >> 2, kq = tl & 3, lr = r & 3;
    int bb = (lr - s) & 3;    // sub-block held at step s (ror brings lower lane's data)
    int k = kq * 32 + 8 * bb + 2 * jj + e;
    Wt[E] = W_hh[k * G4 + g * 128 + r];
  }
}

// ---------------- fused GAT + xw (+ block-local bias/sort/scal) ----------------
__global__ __launch_bounds__(256) void gatxw_kernel(const float* __restrict__ x_seq,
                                                    const int* __restrict__ ei,
                                                    const float* __restrict__ w_gat,
                                                    const float* __restrict__ att_src,
                                                    const float* __restrict__ att_dst,
                                                    const float* __restrict__ b_ih,
                                                    const float* __restrict__ b_hh,
                                                    const float* __restrict__ W_eff,
                                                    const float* __restrict__ biasp,
                                                    float* __restrict__ xw) {
  __shared__ int srt[ET];
  __shared__ int offs[NN + 1];
  __shared__ int cnt[NN];
  __shared__ float xs[256];
  __shared__ float sl[256];
  __shared__ float scal_sh[2];
  int tid = threadIdx.x;
  int posbase = blockIdx.x * 8;
  float we0[NN], we1[NN];
#pragma unroll
  for (int nn = 0; nn < NN; ++nn) {
    we0[nn] = W_eff[nn * G4 + tid];
    we1[nn] = W_eff[nn * G4 + 256 + tid];
  }
  float b0 = b_ih[tid] + b_hh[tid];
  float b1 = b_ih[256 + tid] + b_hh[256 + tid];
#pragma unroll 8
  for (int n = 0; n < NN; ++n) {
    b0 += biasp[n * G4 + tid];
    b1 += biasp[n * G4 + 256 + tid];
  }
  if (tid < NN) cnt[tid] = 0;
  __syncthreads();
  int es = 0, ed = 0, tk = 0;
  if (tid < ET) {
    if (tid < 96) { es = ei[tid]; ed = ei[96 + tid]; }
    else { es = tid - 96; ed = tid - 96; }
    tk = atomicAdd(&cnt[ed], 1);
  }
  __syncthreads();
  if (tid == 0) {
    offs[0] = 0;
    for (int n = 0; n < NN; ++n) offs[n + 1] = offs[n] + cnt[n];
  }
  if (tid == 1) {
    float cs = 0.f, cd = 0.f;
    for (int f = 0; f < FF; ++f) {
      cs = fmaf(w_gat[f], att_src[f], cs);
      cd = fmaf(w_gat[f], att_dst[f], cd);
    }
    scal_sh[0] = cs;
    scal_sh[1] = cd;
  }
  __syncthreads();
  if (tid < ET) srt[offs[ed] + tk] = es;
  xs[tid] = x_seq[posbase * NN + tid];  // coalesced
  __syncthreads();
  float cs = scal_sh[0], cd = scal_sh[1];
  int p = tid >> 5, n = tid & 31;
  int base = p * 32;
  int e0 = offs[n], e1 = offs[n + 1];
  float xn = xs[base + n];
  float cdxn = cd * xn;
  float m = -3.0e38f;
  for (int e = e0; e < e1; ++e) {
    float ev = fmaf(cs, xs[base + srt[e]], cdxn);
    ev = ev > 0.f ? ev : 0.2f * ev;  // LeakyReLU(0.2)
    m = fmaxf(m, ev);
  }
  float z = 0.f, sa = 0.f;
  for (int e = e0; e < e1; ++e) {
    float xsv = xs[base + srt[e]];
    float ev = fmaf(cs, xsv, cdxn);
    ev = ev > 0.f ? ev : 0.2f * ev;
    float ex = __expf(ev - m);
    z += ex;
    sa = fmaf(ex, xsv, sa);
  }
  sl[p * 32 + n] = sa * frcp(z);
  __syncthreads();
  for (int pp = 0; pp < 8; ++pp) {
    const float4* sp = (const float4*)&sl[pp * 32];
    float a0 = b0, a1 = b1;
#pragma unroll
    for (int q = 0; q < 8; ++q) {
      float4 sv = sp[q];
      a0 = fmaf(sv.x, we0[4 * q], a0);
      a0 = fmaf(sv.y, we0[4 * q + 1], a0);
      a0 = fmaf(sv.z, we0[4 * q + 2], a0);
      a0 = fmaf(sv.w, we0[4 * q + 3], a0);
      a1 = fmaf(sv.x, we1[4 * q], a1);
      a1 = fmaf(sv.y, we1[4 * q + 1], a1);
      a1 = fmaf(sv.z, we1[4 * q + 2], a1);
      a1 = fmaf(sv.w, we1[4 * q + 3], a1);
    }
    size_t row = (size_t)(posbase + pp) * G4;
    xw[row + tid] = a0;
    xw[row + 256 + tid] = a1;
  }
}

// ---------------- LSTM scan: R15 — R13 skeleton + DPP ring-share of h ----------------
// R13 was LDS-return-BW bound: 64 ds_read_b128/step (64KB broadcast reads, ~770cy on
// the per-CU LDS pipe) vs ~436cy/SIMD VALU issue; measured 1267cy/step ≈ their sum.
// R15: each lane loads only 8 h floats (2 b128); the 4 same-kq lanes of each 16-lane
// DPP row exchange sub-blocks via v_mov_b32_dpp row_ror:4 between 4 macro-steps.
// Rotation order baked into Wt by prep. Reads/step: 64 -> 16 instr (16KB).
// Quad reduce / gate-split act / x ring / write identical to verified R13.
//
// Reg map: v32-39 h sub-block (4 pairs, rotated) | v64-191 weights | v216-223 acc pairs
// v204-215 tail temps | v224-227 x ring | v194 xaddr | v195/196 rdA/B | v197/198 wrA/B
// v199 c | v200-203 act consts/zero

#define PK4F(HP, W0, W1, W2, W3) \
  "v_pk_fma_f32 v[216:217], v[" HP "], v[" W0 "], 0\n\t" \
  "v_pk_fma_f32 v[218:219], v[" HP "], v[" W1 "], 0\n\t" \
  "v_pk_fma_f32 v[220:221], v[" HP "], v[" W2 "], 0\n\t" \
  "v_pk_fma_f32 v[222:223], v[" HP "], v[" W3 "], 0\n\t"

#define PK4A(HP, W0, W1, W2, W3) \
  "v_pk_fma_f32 v[216:217], v[" HP "], v[" W0 "], v[216:217]\n\t" \
  "v_pk_fma_f32 v[218:219], v[" HP "], v[" W1 "], v[218:219]\n\t" \
  "v_pk_fma_f32 v[220:221], v[" HP "], v[" W2 "], v[220:221]\n\t" \
  "v_pk_fma_f32 v[222:223], v[" HP "], v[" W3 "], v[222:223]\n\t"

// rotate the 4-pair h block to the next sub-block (brings lane i-4's regs, same kq)
#define ROT8 \
  "v_mov_b32_dpp v32, v32 row_ror:4 row_mask:0xf bank_mask:0xf\n\t" \
  "v_mov_b32_dpp v33, v33 row_ror:4 row_mask:0xf bank_mask:0xf\n\t" \
  "v_mov_b32_dpp v34, v34 row_ror:4 row_mask:0xf bank_mask:0xf\n\t" \
  "v_mov_b32_dpp v35, v35 row_ror:4 row_mask:0xf bank_mask:0xf\n\t" \
  "v_mov_b32_dpp v36, v36 row_ror:4 row_mask:0xf bank_mask:0xf\n\t" \
  "v_mov_b32_dpp v37, v37 row_ror:4 row_mask:0xf bank_mask:0xf\n\t" \
  "v_mov_b32_dpp v38, v38 row_ror:4 row_mask:0xf bank_mask:0xf\n\t" \
  "v_mov_b32_dpp v39, v39 row_ror:4 row_mask:0xf bank_mask:0xf\n\t"

#define PHASE(XSLOT, RD, WR) \
  "ds_read_b128 v[32:35], " RD "\n\t" \
  "ds_read_b128 v[36:39], " RD " offset:16\n\t" \
  "s_waitcnt lgkmcnt(1)\n\t" \
  PK4F("32:33", "64:65",   "66:67",   "68:69",   "70:71") \
  PK4A("34:35", "72:73",   "74:75",   "76:77",   "78:79") \
  "s_waitcnt lgkmcnt(0)\n\t" \
  PK4A("36:37", "80:81",   "82:83",   "84:85",   "86:87") \
  PK4A("38:39", "88:89",   "90:91",   "92:93",   "94:95") \
  ROT8 \
  PK4A("32:33", "96:97",   "98:99",   "100:101", "102:103") \
  PK4A("34:35", "104:105", "106:107", "108:109", "110:111") \
  PK4A("36:37", "112:113", "114:115", "116:117", "118:119") \
  PK4A("38:39", "120:121", "122:123", "124:125", "126:127") \
  ROT8 \
  PK4A("32:33", "128:129", "130:131", "132:133", "134:135") \
  PK4A("34:35", "136:137", "138:139", "140:141", "142:143") \
  PK4A("36:37", "144:145", "146:147", "148:149", "150:151") \
  PK4A("38:39", "152:153", "154:155", "156:157", "158:159") \
  ROT8 \
  PK4A("32:33", "160:161", "162:163", "164:165", "166:167") \
  PK4A("34:35", "168:169", "170:171", "172:173", "174:175") \
  PK4A("36:37", "176:177", "178:179", "180:181", "182:183") \
  PK4A("38:39", "184:185", "186:187", "188:189", "190:191") \
  "s_waitcnt vmcnt(3)\n\t" \
  "v_mov_b32 v215, " XSLOT "\n\t" \
  "global_load_dword " XSLOT ", v194, %[xwb]\n\t" \
  "v_add_u32 v194, 0x800, v194\n\t" \
  "v_add_f32 v204, v216, v217\n\t" \
  "v_add_f32 v205, v218, v219\n\t" \
  "v_add_f32 v206, v220, v221\n\t" \
  "v_add_f32 v207, v222, v223\n\t" \
  "v_add_f32_dpp v204, v204, v204 quad_perm:[1,0,3,2] row_mask:0xf bank_mask:0xf\n\t" \
  "v_add_f32_dpp v205, v205, v205 quad_perm:[1,0,3,2] row_mask:0xf bank_mask:0xf\n\t" \
  "v_add_f32_dpp v206, v206, v206 quad_perm:[1,0,3,2] row_mask:0xf bank_mask:0xf\n\t" \
  "v_add_f32_dpp v207, v207, v207 quad_perm:[1,0,3,2] row_mask:0xf bank_mask:0xf\n\t" \
  "v_add_f32_dpp v204, v204, v204 quad_perm:[2,3,0,1] row_mask:0xf bank_mask:0xf\n\t" \
  "v_add_f32_dpp v205, v205, v205 quad_perm:[2,3,0,1] row_mask:0xf bank_mask:0xf\n\t" \
  "v_add_f32_dpp v206, v206, v206 quad_perm:[2,3,0,1] row_mask:0xf bank_mask:0xf\n\t" \
  "v_add_f32_dpp v207, v207, v207 quad_perm:[2,3,0,1] row_mask:0xf bank_mask:0xf\n\t" \
  "v_cndmask_b32 v208, v204, v205, s[22:23]\n\t" \
  "v_cndmask_b32 v209, v206, v207, s[22:23]\n\t" \
  "v_cndmask_b32 v208, v208, v209, s[24:25]\n\t" \
  "v_add_f32 v208, v208, v215\n\t" \
  "v_mul_f32 v209, v200, v208\n\t" \
  "v_exp_f32 v209, v209\n\t" \
  "s_nop 0\n\t" \
  "v_add_f32 v209, 1.0, v209\n\t" \
  "v_rcp_f32 v209, v209\n\t" \
  "s_nop 0\n\t" \
  "v_fma_f32 v210, v201, v209, v202\n\t" \
  "s_nop 1\n\t" \
  "v_add_f32_dpp v211, v210, v203 quad_perm:[0,0,0,0] row_mask:0xf bank_mask:0xf\n\t" \
  "v_add_f32_dpp v212, v210, v203 quad_perm:[1,1,1,1] row_mask:0xf bank_mask:0xf\n\t" \
  "v_add_f32_dpp v213, v210, v203 quad_perm:[2,2,2,2] row_mask:0xf bank_mask:0xf\n\t" \
  "v_add_f32_dpp v214, v210, v203 quad_perm:[3,3,3,3] row_mask:0xf bank_mask:0xf\n\t" \
  "v_mul_f32 v211, v211, v213\n\t" \
  "v_fma_f32 v199, v212, v199, v211\n\t" \
  "v_mul_f32 v209, 0x4038aa3b, v199\n\t" \
  "v_exp_f32 v209, v209\n\t" \
  "s_nop 0\n\t" \
  "v_add_f32 v209, 1.0, v209\n\t" \
  "v_rcp_f32 v209, v209\n\t" \
  "s_nop 0\n\t" \
  "v_fma_f32 v209, -2.0, v209, 1.0\n\t" \
  "v_mul_f32 v209, v214, v209\n\t" \
  "ds_write_b32 " WR ", v209\n\t" \
  "s_waitcnt lgkmcnt(0)\n\t" \
  "s_barrier\n\t"

__global__ __launch_bounds__(512, 2) void lstm_kernel(const float* __restrict__ xw,
                                                      const float* __restrict__ Wt,
                                                      const float* __restrict__ W_fc,
                                                      const float* __restrict__ b_fc,
                                                      float* __restrict__ out) {
  __shared__ __align__(16) float lds[256];  // hA [0,128) floats, hB [128,256), linear h[k]
  int b = blockIdx.x, tid = threadIdx.x;
  int r = tid >> 2, kq = tid & 3;
  int lr = r & 3;                        // row-in-DPP-row; selects loaded sub-block
  if (tid < 256) lds[tid] = 0.f;
  const float* xwb = xw + (size_t)b * TT * G4;
  unsigned xoff0 = (unsigned)((kq * 128 + r) * 4);  // t=0
  unsigned wtoff = (unsigned)(tid * 512);
  unsigned lbase = (unsigned)(uintptr_t)&lds[0];  // LDS aperture is 4GB-aligned
  unsigned rda = lbase + (unsigned)(kq * 128 + lr * 32);  // floats [kq*32+8*lr .. +8)
  unsigned rdb = rda + 512;
  unsigned wra = lbase + (unsigned)(r * 4);               // h[r], 4-way broadcast write
  unsigned wrb = wra + 512;
  // gate-split act constants: lane kq handles gate kq (i,f,o sigmoid; g=2 tanh)
  float kmulf = (kq == 2) ? __uint_as_float(0x4038aa3bu)   //  2*log2e
                          : __uint_as_float(0xbfb8aa3bu);  // -log2e
  float Af = (kq == 2) ? -2.f : 1.f;
  float Bf = (kq == 2) ? 1.f : 0.f;
  unsigned kqodd = kq & 1, kqhi = kq >> 1;
  __syncthreads();
  asm volatile(
    "v_mov_b32 v194, %[xo]\n\t"
    "v_mov_b32 v195, %[rda]\n\t"
    "v_mov_b32 v196, %[rdb]\n\t"
    "v_mov_b32 v197, %[wra]\n\t"
    "v_mov_b32 v198, %[wrb]\n\t"
    "v_mov_b32 v199, 0\n\t"          // c
    "v_mov_b32 v200, %[km]\n\t"      // kmul
    "v_mov_b32 v201, %[Aa]\n\t"      // A
    "v_mov_b32 v202, %[Bb]\n\t"      // B
    "v_mov_b32 v203, 0\n\t"          // zero (DPP-gather src1)
    "v_cmp_eq_u32 s[22:23], 1, %[kodd]\n\t"
    "v_cmp_eq_u32 s[24:25], 1, %[khi]\n\t"
    // x prefetch ring: t=0..3 -> v224..v227
    "global_load_dword v224, v194, %[xwb]\n\t"
    "v_add_u32 v194, 0x800, v194\n\t"
    "global_load_dword v225, v194, %[xwb]\n\t"
    "v_add_u32 v194, 0x800, v194\n\t"
    "global_load_dword v226, v194, %[xwb]\n\t"
    "v_add_u32 v194, 0x800, v194\n\t"
    "global_load_dword v227, v194, %[xwb]\n\t"
    "v_add_u32 v194, 0x800, v194\n\t"
    "global_load_dwordx4 v[64:67], %[wto], %[wtb] offset:0\n\t"
    "global_load_dwordx4 v[68:71], %[wto], %[wtb] offset:16\n\t"
    "global_load_dwordx4 v[72:75], %[wto], %[wtb] offset:32\n\t"
    "global_load_dwordx4 v[76:79], %[wto], %[wtb] offset:48\n\t"
    "global_load_dwordx4 v[80:83], %[wto], %[wtb] offset:64\n\t"
    "global_load_dwordx4 v[84:87], %[wto], %[wtb] offset:80\n\t"
    "global_load_dwordx4 v[88:91], %[wto], %[wtb] offset:96\n\t"
    "global_load_dwordx4 v[92:95], %[wto], %[wtb] offset:112\n\t"
    "global_load_dwordx4 v[96:99], %[wto], %[wtb] offset:128\n\t"
    "global_load_dwordx4 v[100:103], %[wto], %[wtb] offset:144\n\t"
    "global_load_dwordx4 v[104:107], %[wto], %[wtb] offset:160\n\t"
    "global_load_dwordx4 v[108:111], %[wto], %[wtb] offset:176\n\t"
    "global_load_dwordx4 v[112:115], %[wto], %[wtb] offset:192\n\t"
    "global_load_dwordx4 v[116:119], %[wto], %[wtb] offset:208\n\t"
    "global_load_dwordx4 v[120:123], %[wto], %[wtb] offset:224\n\t"
    "global_load_dwordx4 v[124:127], %[wto], %[wtb] offset:240\n\t"
    "global_load_dwordx4 v[128:131], %[wto], %[wtb] offset:256\n\t"
    "global_load_dwordx4 v[132:135], %[wto], %[wtb] offset:272\n\t"
    "global_load_dwordx4 v[136:139], %[wto], %[wtb] offset:288\n\t"
    "global_load_dwordx4 v[140:143], %[wto], %[wtb] offset:304\n\t"
    "global_load_dwordx4 v[144:147], %[wto], %[wtb] offset:320\n\t"
    "global_load_dwordx4 v[148:151], %[wto], %[wtb] offset:336\n\t"
    "global_load_dwordx4 v[152:155], %[wto], %[wtb] offset:352\n\t"
    "global_load_dwordx4 v[156:159], %[wto], %[wtb] offset:368\n\t"
    "global_load_dwordx4 v[160:163], %[wto], %[wtb] offset:384\n\t"
    "global_load_dwordx4 v[164:167], %[wto], %[wtb] offset:400\n\t"
    "global_load_dwordx4 v[168:171], %[wto], %[wtb] offset:416\n\t"
    "global_load_dwordx4 v[172:175], %[wto], %[wtb] offset:432\n\t"
    "global_load_dwordx4 v[176:179], %[wto], %[wtb] offset:448\n\t"
    "global_load_dwordx4 v[180:183], %[wto], %[wtb] offset:464\n\t"
    "global_load_dwordx4 v[184:187], %[wto], %[wtb] offset:480\n\t"
    "global_load_dwordx4 v[188:191], %[wto], %[wtb] offset:496\n\t"
    "s_waitcnt vmcnt(0)\n\t"
    "s_movk_i32 s20, 0x80\n\t"    // 128 iterations x 4 phases = 512 steps
    "L_lstm_%=:\n\t"
    PHASE("v224", "v195", "v198")   // t%4==0: read A, write B
    PHASE("v225", "v196", "v197")   // t%4==1: read B, write A
    PHASE("v226", "v195", "v198")   // t%4==2: read A, write B
    PHASE("v227", "v196", "v197")   // t%4==3: read B, write A
    "s_sub_u32 s20, s20, 1\n\t"
    "s_cmp_lg_u32 s20, 0\n\t"
    "s_cbranch_scc1 L_lstm_%=\n\t"
    "s_waitcnt vmcnt(0) lgkmcnt(0)\n\t"
    :
    : [xwb]"s"(xwb), [wtb]"s"(Wt), [wto]"v"(wtoff), [xo]"v"(xoff0),
      [rda]"v"(rda), [rdb]"v"(rdb), [wra]"v"(wra), [wrb]"v"(wrb),
      [km]"v"(kmulf), [Aa]"v"(Af), [Bb]"v"(Bf),
      [kodd]"v"(kqodd), [khi]"v"(kqhi)
    : "memory", "scc", "s20", "s22", "s23", "s24", "s25",
      "v32","v33","v34","v35","v36","v37","v38","v39",
      "v40","v41","v42","v43","v44","v45","v46","v47",
      "v48","v49","v50","v51","v52","v53","v54","v55",
      "v56","v57","v58","v59","v60","v61","v62","v63",
      "v64","v65","v66","v67","v68","v69","v70","v71",
      "v72","v73","v74","v75","v76","v77","v78","v79",
      "v80","v81","v82","v83","v84","v85","v86","v87",
      "v88","v89","v90","v91","v92","v93","v94","v95",
      "v96","v97","v98","v99","v100","v101","v102","v103",
      "v104","v105","v106","v107","v108","v109","v110","v111",
      "v112","v113","v114","v115","v116","v117","v118","v119",
      "v120","v121","v122","v123","v124","v125","v126","v127",
      "v128","v129","v130","v131","v132","v133","v134","v135",
      "v136","v137","v138","v139","v140","v141","v142","v143",
      "v144","v145","v146","v147","v148","v149","v150","v151",
      "v152","v153","v154","v155","v156","v157","v158","v159",
      "v160","v161","v162","v163","v164","v165","v166","v167",
      "v168","v169","v170","v171","v172","v173","v174","v175",
      "v176","v177","v178","v179","v180","v181","v182","v183",
      "v184","v185","v186","v187","v188","v189","v190","v191",
      "v192","v193","v194","v195","v196","v197","v198","v199",
      "v200","v201","v202","v203","v204","v205","v206","v207",
      "v208","v209","v210","v211","v212","v213","v214","v215",
      "v216","v217","v218","v219","v220","v221","v222","v223",
      "v224","v225","v226","v227");
  __syncthreads();
  // final h (after t=511) is in buffer A: lds[k]
  if (tid < 4) {
    float acc = b_fc[tid];
#pragma unroll 8
    for (int k = 0; k < HH; ++k)
      acc = fmaf(lds[k], W_fc[k * 4 + tid], acc);
    out[b * 4 + tid] = acc;
  }
}

extern "C" void kernel_launch(void* const* d_in, const int* in_sizes, int n_in,
                              void* d_out, int out_size, void* d_ws, size_t ws_size,
                              hipStream_t stream) {
  const float* x_seq   = (const float*)d_in[0];
  const int*   ei      = (const int*)d_in[1];
  const float* w_gat   = (const float*)d_in[2];
  const float* att_src = (const float*)d_in[3];
  const float* att_dst = (const float*)d_in[4];
  const float* b_gat   = (const float*)d_in[5];
  const float* W_ih    = (const float*)d_in[6];
  const float* W_hh    = (const float*)d_in[7];
  const float* b_ih    = (const float*)d_in[8];
  const float* b_hh    = (const float*)d_in[9];
  const float* W_fc    = (const float*)d_in[10];
  const float* b_fc    = (const float*)d_in[11];

  float* ws = (float*)d_ws;
  float* Wt    = ws;                            // 512*128 = 65536 f (16B-aligned)
  float* xw    = Wt + 65536;                    // (16384+8)*512 f (pad rows: 4-deep prefetch)
  float* W_eff = xw + (size_t)(NPOS + 8) * G4;  // 32*512
  float* biasp = W_eff + NN * G4;               // 32*512

  prep_kernel<<<NN, G4, 0, stream>>>(w_gat, b_gat, W_ih, W_hh, W_eff, biasp, Wt);
  gatxw_kernel<<<NPOS / 8, 256, 0, stream>>>(x_seq, ei, w_gat, att_src, att_dst,
                                             b_ih, b_hh, W_eff, biasp, xw);
  lstm_kernel<<<BB, 512, 0, stream>>>(xw, Wt, W_fc, b_fc, (float*)d_out);
}

// Round 3
// 410.732 us; speedup vs baseline: 1.0041x; 1.0041x over previous
//
#include <hip/hip_runtime.h>

#define NN 32      // nodes
#define FF 64      // GAT out features
#define HH 128     // LSTM hidden
#define G4 512     // 4*H
#define BB 32      // batch
#define TT 512     // time steps
#define ET 128     // 96 edges + 32 self loops
#define NPOS (BB*TT)

__device__ __forceinline__ float frcp(float x) { return __builtin_amdgcn_rcpf(x); }

// ---------------- prep: fold GAT linear into LSTM input weights + Wt transpose ----------------
// R16 weight layout (DPP ring-share + parity-swizzled halves): lstm thread tid = r*4+kq,
// lr = r&3, s = kq&1. Lane holds h chunk c = kq*4 + ((lr - st)&3) at macro-step st.
// Register v32+iw holds h[c*8 + ((s^(iw>>2))<<2) + (iw&3)]  (instr1 reads half s, instr2 half 1-s
// -> per-instruction bank quads lr*8+s*4: 8 quads x 2 addrs = 2-way = free).
// Wt[tid*128 + st*32 + jj*8 + g*2 + e]: iw = 2*jj+e,
//   k = kq*32 + 8*((lr-st)&3) + ((s^(iw>>2))<<2) + (iw&3);  Wt = W_hh[k][g*128 + r]
__global__ __launch_bounds__(512) void prep_kernel(const float* __restrict__ w_gat,
                                                   const float* __restrict__ b_gat,
                                                   const float* __restrict__ W_ih,
                                                   const float* __restrict__ W_hh,
                                                   float* __restrict__ W_eff,
                                                   float* __restrict__ biasp,
                                                   float* __restrict__ Wt) {
  int j = threadIdx.x;
  int n = blockIdx.x;
  float accw = 0.f, accb = 0.f;
#pragma unroll 8
  for (int f = 0; f < FF; ++f) {
    float wv = W_ih[(n * FF + f) * G4 + j];
    accw = fmaf(w_gat[f], wv, accw);
    accb = fmaf(b_gat[f], wv, accb);
  }
  W_eff[n * G4 + j] = accw;
  biasp[n * G4 + j] = accb;
  int g0 = (n * G4 + j) * 4;
#pragma unroll
  for (int q = 0; q < 4; ++q) {
    int E = g0 + q;
    int tl = E >> 7;          // lstm thread 0..511
    int idx = E & 127;
    int st = idx >> 5;        // macro-step 0..3
    int jj = (idx >> 3) & 3;  // h pair within chunk
    int g = (idx >> 1) & 3;   // gate
    int e = idx & 1;
    int r = tl >> 2, kq = tl & 3, lr = r & 3;
    int bb = (lr - st) & 3;   // chunk held at step st (ror brings lower lane's data)
    int iw = 2 * jj + e;      // register slot within v32..v39
    int sw = (kq & 1) ^ (iw >> 2);  // parity-swizzled half
    int k = kq * 32 + 8 * bb + sw * 4 + (iw & 3);
    Wt[E] = W_hh[k * G4 + g * 128 + r];
  }
}

// ---------------- fused GAT + xw (+ block-local bias/sort/scal) ----------------
__global__ __launch_bounds__(256) void gatxw_kernel(const float* __restrict__ x_seq,
                                                    const int* __restrict__ ei,
                                                    const float* __restrict__ w_gat,
                                                    const float* __restrict__ att_src,
                                                    const float* __restrict__ att_dst,
                                                    const float* __restrict__ b_ih,
                                                    const float* __restrict__ b_hh,
                                                    const float* __restrict__ W_eff,
                                                    const float* __restrict__ biasp,
                                                    float* __restrict__ xw) {
  __shared__ int srt[ET];
  __shared__ int offs[NN + 1];
  __shared__ int cnt[NN];
  __shared__ float xs[256];
  __shared__ float sl[256];
  __shared__ float scal_sh[2];
  int tid = threadIdx.x;
  int posbase = blockIdx.x * 8;
  float we0[NN], we1[NN];
#pragma unroll
  for (int nn = 0; nn < NN; ++nn) {
    we0[nn] = W_eff[nn * G4 + tid];
    we1[nn] = W_eff[nn * G4 + 256 + tid];
  }
  float b0 = b_ih[tid] + b_hh[tid];
  float b1 = b_ih[256 + tid] + b_hh[256 + tid];
#pragma unroll 8
  for (int n = 0; n < NN; ++n) {
    b0 += biasp[n * G4 + tid];
    b1 += biasp[n * G4 + 256 + tid];
  }
  if (tid < NN) cnt[tid] = 0;
  __syncthreads();
  int es = 0, ed = 0, tk = 0;
  if (tid < ET) {
    if (tid < 96) { es = ei[tid]; ed = ei[96 + tid]; }
    else { es = tid - 96; ed = tid - 96; }
    tk = atomicAdd(&cnt[ed], 1);
  }
  __syncthreads();
  if (tid == 0) {
    offs[0] = 0;
    for (int n = 0; n < NN; ++n) offs[n + 1] = offs[n] + cnt[n];
  }
  if (tid == 1) {
    float cs = 0.f, cd = 0.f;
    for (int f = 0; f < FF; ++f) {
      cs = fmaf(w_gat[f], att_src[f], cs);
      cd = fmaf(w_gat[f], att_dst[f], cd);
    }
    scal_sh[0] = cs;
    scal_sh[1] = cd;
  }
  __syncthreads();
  if (tid < ET) srt[offs[ed] + tk] = es;
  xs[tid] = x_seq[posbase * NN + tid];  // coalesced
  __syncthreads();
  float cs = scal_sh[0], cd = scal_sh[1];
  int p = tid >> 5, n = tid & 31;
  int base = p * 32;
  int e0 = offs[n], e1 = offs[n + 1];
  float xn = xs[base + n];
  float cdxn = cd * xn;
  float m = -3.0e38f;
  for (int e = e0; e < e1; ++e) {
    float ev = fmaf(cs, xs[base + srt[e]], cdxn);
    ev = ev > 0.f ? ev : 0.2f * ev;  // LeakyReLU(0.2)
    m = fmaxf(m, ev);
  }
  float z = 0.f, sa = 0.f;
  for (int e = e0; e < e1; ++e) {
    float xsv = xs[base + srt[e]];
    float ev = fmaf(cs, xsv, cdxn);
    ev = ev > 0.f ? ev : 0.2f * ev;
    float ex = __expf(ev - m);
    z += ex;
    sa = fmaf(ex, xsv, sa);
  }
  sl[p * 32 + n] = sa * frcp(z);
  __syncthreads();
  for (int pp = 0; pp < 8; ++pp) {
    const float4* sp = (const float4*)&sl[pp * 32];
    float a0 = b0, a1 = b1;
#pragma unroll
    for (int q = 0; q < 8; ++q) {
      float4 sv = sp[q];
      a0 = fmaf(sv.x, we0[4 * q], a0);
      a0 = fmaf(sv.y, we0[4 * q + 1], a0);
      a0 = fmaf(sv.z, we0[4 * q + 2], a0);
      a0 = fmaf(sv.w, we0[4 * q + 3], a0);
      a1 = fmaf(sv.x, we1[4 * q], a1);
      a1 = fmaf(sv.y, we1[4 * q + 1], a1);
      a1 = fmaf(sv.z, we1[4 * q + 2], a1);
      a1 = fmaf(sv.w, we1[4 * q + 3], a1);
    }
    size_t row = (size_t)(posbase + pp) * G4;
    xw[row + tid] = a0;
    xw[row + 256 + tid] = a1;
  }
}

// ---------------- LSTM scan: R16 — R15 ring-share + 2-way bank-swizzled reads ----------------
// R13 (64 clean b128/step) and R15 (16 b128 x 4-way conflict) had IDENTICAL LDS drain
// (~768cy): conflict cancelled the traffic cut. R16 keeps 16 reads but splits each chunk's
// two 16B halves across kq parity -> per-instruction addresses land on 8 bank-quads x 2
// = 2-way, which is free (m136). Weight order compensates in prep. Drain ~768 -> ~190cy.
//
// Reg map: v32-39 h chunk (rotated) | v64-191 weights | v216-223 acc pairs
// v204-215 tail temps | v224-227 x ring | v194 xaddr | v195/192 rdA1/rdA2
// v196/193 rdB1/rdB2 | v197/198 wrA/B | v199 c | v200-203 act consts/zero

#define PK4F(HP, W0, W1, W2, W3) \
  "v_pk_fma_f32 v[216:217], v[" HP "], v[" W0 "], 0\n\t" \
  "v_pk_fma_f32 v[218:219], v[" HP "], v[" W1 "], 0\n\t" \
  "v_pk_fma_f32 v[220:221], v[" HP "], v[" W2 "], 0\n\t" \
  "v_pk_fma_f32 v[222:223], v[" HP "], v[" W3 "], 0\n\t"

#define PK4A(HP, W0, W1, W2, W3) \
  "v_pk_fma_f32 v[216:217], v[" HP "], v[" W0 "], v[216:217]\n\t" \
  "v_pk_fma_f32 v[218:219], v[" HP "], v[" W1 "], v[218:219]\n\t" \
  "v_pk_fma_f32 v[220:221], v[" HP "], v[" W2 "], v[220:221]\n\t" \
  "v_pk_fma_f32 v[222:223], v[" HP "], v[" W3 "], v[222:223]\n\t"

// rotate the 4-pair h block to the next chunk (brings lane i-4's regs, same kq)
#define ROT8 \
  "v_mov_b32_dpp v32, v32 row_ror:4 row_mask:0xf bank_mask:0xf\n\t" \
  "v_mov_b32_dpp v33, v33 row_ror:4 row_mask:0xf bank_mask:0xf\n\t" \
  "v_mov_b32_dpp v34, v34 row_ror:4 row_mask:0xf bank_mask:0xf\n\t" \
  "v_mov_b32_dpp v35, v35 row_ror:4 row_mask:0xf bank_mask:0xf\n\t" \
  "v_mov_b32_dpp v36, v36 row_ror:4 row_mask:0xf bank_mask:0xf\n\t" \
  "v_mov_b32_dpp v37, v37 row_ror:4 row_mask:0xf bank_mask:0xf\n\t" \
  "v_mov_b32_dpp v38, v38 row_ror:4 row_mask:0xf bank_mask:0xf\n\t" \
  "v_mov_b32_dpp v39, v39 row_ror:4 row_mask:0xf bank_mask:0xf\n\t"

#define PHASE(XSLOT, RD1, RD2, WR) \
  "ds_read_b128 v[32:35], " RD1 "\n\t" \
  "ds_read_b128 v[36:39], " RD2 "\n\t" \
  "s_waitcnt lgkmcnt(1)\n\t" \
  PK4F("32:33", "64:65",   "66:67",   "68:69",   "70:71") \
  PK4A("34:35", "72:73",   "74:75",   "76:77",   "78:79") \
  "s_waitcnt lgkmcnt(0)\n\t" \
  PK4A("36:37", "80:81",   "82:83",   "84:85",   "86:87") \
  PK4A("38:39", "88:89",   "90:91",   "92:93",   "94:95") \
  ROT8 \
  PK4A("32:33", "96:97",   "98:99",   "100:101", "102:103") \
  PK4A("34:35", "104:105", "106:107", "108:109", "110:111") \
  PK4A("36:37", "112:113", "114:115", "116:117", "118:119") \
  PK4A("38:39", "120:121", "122:123", "124:125", "126:127") \
  ROT8 \
  PK4A("32:33", "128:129", "130:131", "132:133", "134:135") \
  PK4A("34:35", "136:137", "138:139", "140:141", "142:143") \
  PK4A("36:37", "144:145", "146:147", "148:149", "150:151") \
  PK4A("38:39", "152:153", "154:155", "156:157", "158:159") \
  ROT8 \
  PK4A("32:33", "160:161", "162:163", "164:165", "166:167") \
  PK4A("34:35", "168:169", "170:171", "172:173", "174:175") \
  PK4A("36:37", "176:177", "178:179", "180:181", "182:183") \
  PK4A("38:39", "184:185", "186:187", "188:189", "190:191") \
  "s_waitcnt vmcnt(3)\n\t" \
  "v_mov_b32 v215, " XSLOT "\n\t" \
  "global_load_dword " XSLOT ", v194, %[xwb]\n\t" \
  "v_add_u32 v194, 0x800, v194\n\t" \
  "v_add_f32 v204, v216, v217\n\t" \
  "v_add_f32 v205, v218, v219\n\t" \
  "v_add_f32 v206, v220, v221\n\t" \
  "v_add_f32 v207, v222, v223\n\t" \
  "v_add_f32_dpp v204, v204, v204 quad_perm:[1,0,3,2] row_mask:0xf bank_mask:0xf\n\t" \
  "v_add_f32_dpp v205, v205, v205 quad_perm:[1,0,3,2] row_mask:0xf bank_mask:0xf\n\t" \
  "v_add_f32_dpp v206, v206, v206 quad_perm:[1,0,3,2] row_mask:0xf bank_mask:0xf\n\t" \
  "v_add_f32_dpp v207, v207, v207 quad_perm:[1,0,3,2] row_mask:0xf bank_mask:0xf\n\t" \
  "v_add_f32_dpp v204, v204, v204 quad_perm:[2,3,0,1] row_mask:0xf bank_mask:0xf\n\t" \
  "v_add_f32_dpp v205, v205, v205 quad_perm:[2,3,0,1] row_mask:0xf bank_mask:0xf\n\t" \
  "v_add_f32_dpp v206, v206, v206 quad_perm:[2,3,0,1] row_mask:0xf bank_mask:0xf\n\t" \
  "v_add_f32_dpp v207, v207, v207 quad_perm:[2,3,0,1] row_mask:0xf bank_mask:0xf\n\t" \
  "v_cndmask_b32 v208, v204, v205, s[22:23]\n\t" \
  "v_cndmask_b32 v209, v206, v207, s[22:23]\n\t" \
  "v_cndmask_b32 v208, v208, v209, s[24:25]\n\t" \
  "v_add_f32 v208, v208, v215\n\t" \
  "v_mul_f32 v209, v200, v208\n\t" \
  "v_exp_f32 v209, v209\n\t" \
  "s_nop 0\n\t" \
  "v_add_f32 v209, 1.0, v209\n\t" \
  "v_rcp_f32 v209, v209\n\t" \
  "s_nop 0\n\t" \
  "v_fma_f32 v210, v201, v209, v202\n\t" \
  "s_nop 1\n\t" \
  "v_add_f32_dpp v211, v210, v203 quad_perm:[0,0,0,0] row_mask:0xf bank_mask:0xf\n\t" \
  "v_add_f32_dpp v212, v210, v203 quad_perm:[1,1,1,1] row_mask:0xf bank_mask:0xf\n\t" \
  "v_add_f32_dpp v213, v210, v203 quad_perm:[2,2,2,2] row_mask:0xf bank_mask:0xf\n\t" \
  "v_add_f32_dpp v214, v210, v203 quad_perm:[3,3,3,3] row_mask:0xf bank_mask:0xf\n\t" \
  "v_mul_f32 v211, v211, v213\n\t" \
  "v_fma_f32 v199, v212, v199, v211\n\t" \
  "v_mul_f32 v209, 0x4038aa3b, v199\n\t" \
  "v_exp_f32 v209, v209\n\t" \
  "s_nop 0\n\t" \
  "v_add_f32 v209, 1.0, v209\n\t" \
  "v_rcp_f32 v209, v209\n\t" \
  "s_nop 0\n\t" \
  "v_fma_f32 v209, -2.0, v209, 1.0\n\t" \
  "v_mul_f32 v209, v214, v209\n\t" \
  "ds_write_b32 " WR ", v209\n\t" \
  "s_waitcnt lgkmcnt(0)\n\t" \
  "s_barrier\n\t"

__global__ __launch_bounds__(512, 2) void lstm_kernel(const float* __restrict__ xw,
                                                      const float* __restrict__ Wt,
                                                      const float* __restrict__ W_fc,
                                                      const float* __restrict__ b_fc,
                                                      float* __restrict__ out) {
  __shared__ __align__(16) float lds[256];  // hA [0,128) floats, hB [128,256), linear h[k]
  int b = blockIdx.x, tid = threadIdx.x;
  int r = tid >> 2, kq = tid & 3;
  int lr = r & 3;                        // row-in-DPP-row; selects loaded chunk
  if (tid < 256) lds[tid] = 0.f;
  const float* xwb = xw + (size_t)b * TT * G4;
  unsigned xoff0 = (unsigned)((kq * 128 + r) * 4);  // t=0
  unsigned wtoff = (unsigned)(tid * 512);
  unsigned lbase = (unsigned)(uintptr_t)&lds[0];  // LDS aperture is 4GB-aligned
  unsigned c0b = (unsigned)((kq * 4 + lr) * 32);  // chunk byte offset (step-0 chunk)
  unsigned s16 = (unsigned)((kq & 1) * 16);       // parity half
  unsigned rda1 = lbase + c0b + s16;              // instr1: half s
  unsigned rda2 = lbase + c0b + 16 - s16;         // instr2: half 1-s
  unsigned rdb1 = rda1 + 512;
  unsigned rdb2 = rda2 + 512;
  unsigned wra = lbase + (unsigned)(r * 4);       // h[r], 4-way broadcast write
  unsigned wrb = wra + 512;
  // gate-split act constants: lane kq handles gate kq (i,f,o sigmoid; g=2 tanh)
  float kmulf = (kq == 2) ? __uint_as_float(0x4038aa3bu)   //  2*log2e
                          : __uint_as_float(0xbfb8aa3bu);  // -log2e
  float Af = (kq == 2) ? -2.f : 1.f;
  float Bf = (kq == 2) ? 1.f : 0.f;
  unsigned kqodd = kq & 1, kqhi = kq >> 1;
  __syncthreads();
  asm volatile(
    "v_mov_b32 v194, %[xo]\n\t"
    "v_mov_b32 v195, %[ra1]\n\t"
    "v_mov_b32 v192, %[ra2]\n\t"
    "v_mov_b32 v196, %[rb1]\n\t"
    "v_mov_b32 v193, %[rb2]\n\t"
    "v_mov_b32 v197, %[wra]\n\t"
    "v_mov_b32 v198, %[wrb]\n\t"
    "v_mov_b32 v199, 0\n\t"          // c
    "v_mov_b32 v200, %[km]\n\t"      // kmul
    "v_mov_b32 v201, %[Aa]\n\t"      // A
    "v_mov_b32 v202, %[Bb]\n\t"      // B
    "v_mov_b32 v203, 0\n\t"          // zero (DPP-gather src1)
    "v_cmp_eq_u32 s[22:23], 1, %[kodd]\n\t"
    "v_cmp_eq_u32 s[24:25], 1, %[khi]\n\t"
    // x prefetch ring: t=0..3 -> v224..v227
    "global_load_dword v224, v194, %[xwb]\n\t"
    "v_add_u32 v194, 0x800, v194\n\t"
    "global_load_dword v225, v194, %[xwb]\n\t"
    "v_add_u32 v194, 0x800, v194\n\t"
    "global_load_dword v226, v194, %[xwb]\n\t"
    "v_add_u32 v194, 0x800, v194\n\t"
    "global_load_dword v227, v194, %[xwb]\n\t"
    "v_add_u32 v194, 0x800, v194\n\t"
    "global_load_dwordx4 v[64:67], %[wto], %[wtb] offset:0\n\t"
    "global_load_dwordx4 v[68:71], %[wto], %[wtb] offset:16\n\t"
    "global_load_dwordx4 v[72:75], %[wto], %[wtb] offset:32\n\t"
    "global_load_dwordx4 v[76:79], %[wto], %[wtb] offset:48\n\t"
    "global_load_dwordx4 v[80:83], %[wto], %[wtb] offset:64\n\t"
    "global_load_dwordx4 v[84:87], %[wto], %[wtb] offset:80\n\t"
    "global_load_dwordx4 v[88:91], %[wto], %[wtb] offset:96\n\t"
    "global_load_dwordx4 v[92:95], %[wto], %[wtb] offset:112\n\t"
    "global_load_dwordx4 v[96:99], %[wto], %[wtb] offset:128\n\t"
    "global_load_dwordx4 v[100:103], %[wto], %[wtb] offset:144\n\t"
    "global_load_dwordx4 v[104:107], %[wto], %[wtb] offset:160\n\t"
    "global_load_dwordx4 v[108:111], %[wto], %[wtb] offset:176\n\t"
    "global_load_dwordx4 v[112:115], %[wto], %[wtb] offset:192\n\t"
    "global_load_dwordx4 v[116:119], %[wto], %[wtb] offset:208\n\t"
    "global_load_dwordx4 v[120:123], %[wto], %[wtb] offset:224\n\t"
    "global_load_dwordx4 v[124:127], %[wto], %[wtb] offset:240\n\t"
    "global_load_dwordx4 v[128:131], %[wto], %[wtb] offset:256\n\t"
    "global_load_dwordx4 v[132:135], %[wto], %[wtb] offset:272\n\t"
    "global_load_dwordx4 v[136:139], %[wto], %[wtb] offset:288\n\t"
    "global_load_dwordx4 v[140:143], %[wto], %[wtb] offset:304\n\t"
    "global_load_dwordx4 v[144:147], %[wto], %[wtb] offset:320\n\t"
    "global_load_dwordx4 v[148:151], %[wto], %[wtb] offset:336\n\t"
    "global_load_dwordx4 v[152:155], %[wto], %[wtb] offset:352\n\t"
    "global_load_dwordx4 v[156:159], %[wto], %[wtb] offset:368\n\t"
    "global_load_dwordx4 v[160:163], %[wto], %[wtb] offset:384\n\t"
    "global_load_dwordx4 v[164:167], %[wto], %[wtb] offset:400\n\t"
    "global_load_dwordx4 v[168:171], %[wto], %[wtb] offset:416\n\t"
    "global_load_dwordx4 v[172:175], %[wto], %[wtb] offset:432\n\t"
    "global_load_dwordx4 v[176:179], %[wto], %[wtb] offset:448\n\t"
    "global_load_dwordx4 v[180:183], %[wto], %[wtb] offset:464\n\t"
    "global_load_dwordx4 v[184:187], %[wto], %[wtb] offset:480\n\t"
    "global_load_dwordx4 v[188:191], %[wto], %[wtb] offset:496\n\t"
    "s_waitcnt vmcnt(0)\n\t"
    "s_movk_i32 s20, 0x80\n\t"    // 128 iterations x 4 phases = 512 steps
    "L_lstm_%=:\n\t"
    PHASE("v224", "v195", "v192", "v198")   // t%4==0: read A, write B
    PHASE("v225", "v196", "v193", "v197")   // t%4==1: read B, write A
    PHASE("v226", "v195", "v192", "v198")   // t%4==2: read A, write B
    PHASE("v227", "v196", "v193", "v197")   // t%4==3: read B, write A
    "s_sub_u32 s20, s20, 1\n\t"
    "s_cmp_lg_u32 s20, 0\n\t"
    "s_cbranch_scc1 L_lstm_%=\n\t"
    "s_waitcnt vmcnt(0) lgkmcnt(0)\n\t"
    :
    : [xwb]"s"(xwb), [wtb]"s"(Wt), [wto]"v"(wtoff), [xo]"v"(xoff0),
      [ra1]"v"(rda1), [ra2]"v"(rda2), [rb1]"v"(rdb1), [rb2]"v"(rdb2),
      [wra]"v"(wra), [wrb]"v"(wrb),
      [km]"v"(kmulf), [Aa]"v"(Af), [Bb]"v"(Bf),
      [kodd]"v"(kqodd), [khi]"v"(kqhi)
    : "memory", "scc", "s20", "s22", "s23", "s24", "s25",
      "v32","v33","v34","v35","v36","v37","v38","v39",
      "v40","v41","v42","v43","v44","v45","v46","v47",
      "v48","v49","v50","v51","v52","v53","v54","v55",
      "v56","v57","v58","v59","v60","v61","v62","v63",
      "v64","v65","v66","v67","v68","v69","v70","v71",
      "v72","v73","v74","v75","v76","v77","v78","v79",
      "v80","v81","v82","v83","v84","v85","v86","v87",
      "v88","v89","v90","v91","v92","v93","v94","v95",
      "v96","v97","v98","v99","v100","v101","v102","v103",
      "v104","v105","v106","v107","v108","v109","v110","v111",
      "v112","v113","v114","v115","v116","v117","v118","v119",
      "v120","v121","v122","v123","v124","v125","v126","v127",
      "v128","v129","v130","v131","v132","v133","v134","v135",
      "v136","v137","v138","v139","v140","v141","v142","v143",
      "v144","v145","v146","v147","v148","v149","v150","v151",
      "v152","v153","v154","v155","v156","v157","v158","v159",
      "v160","v161","v162","v163","v164","v165","v166","v167",
      "v168","v169","v170","v171","v172","v173","v174","v175",
      "v176","v177","v178","v179","v180","v181","v182","v183",
      "v184","v185","v186","v187","v188","v189","v190","v191",
      "v192","v193","v194","v195","v196","v197","v198","v199",
      "v200","v201","v202","v203","v204","v205","v206","v207",
      "v208","v209","v210","v211","v212","v213","v214","v215",
      "v216","v217","v218","v219","v220","v221","v222","v223",
      "v224","v225","v226","v227");
  __syncthreads();
  // final h (after t=511) is in buffer A: lds[k]
  if (tid < 4) {
    float acc = b_fc[tid];
#pragma unroll 8
    for (int k = 0; k < HH; ++k)
      acc = fmaf(lds[k], W_fc[k * 4 + tid], acc);
    out[b * 4 + tid] = acc;
  }
}

extern "C" void kernel_launch(void* const* d_in, const int* in_sizes, int n_in,
                              void* d_out, int out_size, void* d_ws, size_t ws_size,
                              hipStream_t stream) {
  const float* x_seq   = (const float*)d_in[0];
  const int*   ei      = (const int*)d_in[1];
  const float* w_gat   = (const float*)d_in[2];
  const float* att_src = (const float*)d_in[3];
  const float* att_dst = (const float*)d_in[4];
  const float* b_gat   = (const float*)d_in[5];
  const float* W_ih    = (const float*)d_in[6];
  const float* W_hh    = (const float*)d_in[7];
  const float* b_ih    = (const float*)d_in[8];
  const float* b_hh    = (const float*)d_in[9];
  const float* W_fc    = (const float*)d_in[10];
  const float* b_fc    = (const float*)d_in[11];

  float* ws = (float*)d_ws;
  float* Wt    = ws;                            // 512*128 = 65536 f (16B-aligned)
  float* xw    = Wt + 65536;                    // (16384+8)*512 f (pad rows: 4-deep prefetch)
  float* W_eff = xw + (size_t)(NPOS + 8) * G4;  // 32*512
  float* biasp = W_eff + NN * G4;               // 32*512

  prep_kernel<<<NN, G4, 0, stream>>>(w_gat, b_gat, W_ih, W_hh, W_eff, biasp, Wt);
  gatxw_kernel<<<NPOS / 8, 256, 0, stream>>>(x_seq, ei, w_gat, att_src, att_dst,
                                             b_ih, b_hh, W_eff, biasp, xw);
  lstm_kernel<<<BB, 512, 0, stream>>>(xw, Wt, W_fc, b_fc, (float*)d_out);
}